// Round 2
// baseline (276.851 us; speedup 1.0000x reference)
//
#include <hip/hip_runtime.h>

typedef unsigned short u16;
typedef unsigned int u32;

typedef __bf16 bf16x8 __attribute__((ext_vector_type(8)));
typedef float f32x4 __attribute__((ext_vector_type(4)));

__device__ __forceinline__ u16 f2bf(float f) {
  u32 u = __float_as_uint(f);
  u = u + 0x7fffu + ((u >> 16) & 1u);
  return (u16)(u >> 16);
}
__device__ __forceinline__ float bf2f(u16 u) {
  return __uint_as_float(((u32)u) << 16);
}

// strict-< insertion keeps earliest index on ties (matches jax.lax.top_k)
__device__ __forceinline__ void ins3(float d, int s,
                                     float& d0, float& d1, float& d2,
                                     int& i0, int& i1, int& i2) {
  if (d < d2) {
    if (d < d1) {
      d2 = d1; i2 = i1;
      if (d < d0) { d1 = d0; i1 = i0; d0 = d; i0 = s; }
      else        { d1 = d; i1 = s; }
    } else { d2 = d; i2 = s; }
  }
}

// branchless strict-< top-3 insert: 3 cmp + 10 cndmask
__device__ __forceinline__ void ins3b(float d, int s,
                                      float& d0, float& d1, float& d2,
                                      int& i0, int& i1, int& i2) {
  bool c2 = d < d2, c1 = d < d1, c0 = d < d0;
  d2 = c1 ? d1 : (c2 ? d : d2);
  i2 = c1 ? i1 : (c2 ? s : i2);
  d1 = c0 ? d0 : (c1 ? d : d1);
  i1 = c0 ? i0 : (c1 ? s : i1);
  d0 = c0 ? d : d0;
  i0 = c0 ? s : i0;
}

// ---------------------------------------------------------------- weights -> bf16 in MFMA-fragment order + zero BN stat accumulators
// W1f layout: [kt=12][g=16][lane=64][e=8] : element = W1[g*16 + (l&15)][kt*32 + (l>>4)*8 + e]
// W2f layout: [kt= 8][g= 8][lane=64][e=8] : element = W2[g*16 + (l&15)][kt*32 + (l>>4)*8 + e]
__global__ __launch_bounds__(256) void conv_w_kernel(
    const float* __restrict__ W1, const float* __restrict__ W2,
    u16* __restrict__ W1f, u16* __restrict__ W2f, float* __restrict__ stats) {
  int i = blockIdx.x * 256 + threadIdx.x;      // 512 blocks * 256 = 131072 exactly
  if (i < 98304) {
    int e = i & 7, l = (i >> 3) & 63, g = (i >> 9) & 15, kt = i >> 13;
    int col = g * 16 + (l & 15);
    int k = kt * 32 + (l >> 4) * 8 + e;
    W1f[i] = f2bf(W1[col * 384 + k]);
  } else {
    int j = i - 98304;                         // 0..32767
    int e = j & 7, l = (j >> 3) & 63, g = (j >> 9) & 7, kt = j >> 12;
    int col = g * 16 + (l & 15);
    int k = kt * 32 + (l >> 4) * 8 + e;
    W2f[j] = f2bf(W2[col * 256 + k]);
  }
  if (i < 768) stats[i] = 0.f;                 // gs1[256] gq1[256] gs2[128] gq2[128]
}

// ---------------------------------------------------------------- 3NN: indices + weights per point
// Block: 256 threads = 64 target points, 2 points per thread x 8 sub-scans of
// 128 sources. One ds_read_b128 serves TWO point-distance computations (halves
// LDS issue per pair) and each thread runs 4 independent cmp->cndmask chains
// of length 64 (ILP). Contiguous ascending chunk split keeps tie-break exact.
// LDS ~28.8KB -> 5 blocks/CU.
__global__ __launch_bounds__(256) void knn_kernel(
    const float* __restrict__ txyz, const float* __restrict__ sxyz,
    float4* __restrict__ nn) {
  __shared__ float4 sP[1032];      // padded: index s + (s>>7) -> 8 sub-chunks on disjoint banks
  __shared__ float  md[64 * 24];
  __shared__ int    mi[64 * 24];

  const int t = threadIdx.x;
  const int b = blockIdx.x >> 6;              // grid 1024 = 16 batches * 64 groups
  const int n0 = (blockIdx.x & 63) << 6;      // 64 points per block

  const float* sb = sxyz + (size_t)b * 1024 * 3;
  for (int i = t; i < 1024; i += 256) {
    float x = sb[i * 3 + 0], y = sb[i * 3 + 1], z = sb[i * 3 + 2];
    float r2 = __fadd_rn(__fadd_rn(__fmul_rn(x, x), __fmul_rn(y, y)), __fmul_rn(z, z));
    sP[i + (i >> 7)] = make_float4(x, y, z, r2);
  }
  __syncthreads();

  const int pp = t >> 3, sub = t & 7;
  const int nA = n0 + pp * 2;                 // this thread's two points: nA, nA+1
  const float* ta = txyz + ((size_t)b * 4096 + nA) * 3;
  const float a0 = ta[0], a1 = ta[1], a2 = ta[2];
  const float b0 = ta[3], b1 = ta[4], b2 = ta[5];
  const float q2a = __fadd_rn(__fadd_rn(__fmul_rn(a0, a0), __fmul_rn(a1, a1)), __fmul_rn(a2, a2));
  const float q2b = __fadd_rn(__fadd_rn(__fmul_rn(b0, b0), __fmul_rn(b1, b1)), __fmul_rn(b2, b2));

  // trackers: A/B = point A streams 0/1, C/D = point B streams 0/1
  float dA0 = 1e30f, dA1 = 1e30f, dA2 = 1e30f; int iA0 = 0, iA1 = 0, iA2 = 0;
  float dB0 = 1e30f, dB1 = 1e30f, dB2 = 1e30f; int iB0 = 0, iB1 = 0, iB2 = 0;
  float dC0 = 1e30f, dC1 = 1e30f, dC2 = 1e30f; int iC0 = 0, iC1 = 0, iC2 = 0;
  float dD0 = 1e30f, dD1 = 1e30f, dD2 = 1e30f; int iD0 = 0, iD1 = 0, iD2 = 0;
  const int sbeg = sub * 128;

#pragma unroll 4
  for (int off = 0; off < 64; ++off) {
    const int s0 = sbeg + off;
    const int s1 = sbeg + 64 + off;
    float4 p0 = sP[s0 + (s0 >> 7)];
    float4 p1 = sP[s1 + (s1 >> 7)];

    float c00 = __fmul_rn(a0, p0.x);
    c00 = __fadd_rn(c00, __fmul_rn(a1, p0.y));
    c00 = __fadd_rn(c00, __fmul_rn(a2, p0.z));
    float d00 = fmaxf(__fadd_rn(__fadd_rn(q2a, p0.w), __fmul_rn(-2.0f, c00)), 0.0f);

    float c01 = __fmul_rn(a0, p1.x);
    c01 = __fadd_rn(c01, __fmul_rn(a1, p1.y));
    c01 = __fadd_rn(c01, __fmul_rn(a2, p1.z));
    float d01 = fmaxf(__fadd_rn(__fadd_rn(q2a, p1.w), __fmul_rn(-2.0f, c01)), 0.0f);

    float c10 = __fmul_rn(b0, p0.x);
    c10 = __fadd_rn(c10, __fmul_rn(b1, p0.y));
    c10 = __fadd_rn(c10, __fmul_rn(b2, p0.z));
    float d10 = fmaxf(__fadd_rn(__fadd_rn(q2b, p0.w), __fmul_rn(-2.0f, c10)), 0.0f);

    float c11 = __fmul_rn(b0, p1.x);
    c11 = __fadd_rn(c11, __fmul_rn(b1, p1.y));
    c11 = __fadd_rn(c11, __fmul_rn(b2, p1.z));
    float d11 = fmaxf(__fadd_rn(__fadd_rn(q2b, p1.w), __fmul_rn(-2.0f, c11)), 0.0f);

    ins3b(d00, s0, dA0, dA1, dA2, iA0, iA1, iA2);
    ins3b(d01, s1, dB0, dB1, dB2, iB0, iB1, iB2);
    ins3b(d10, s0, dC0, dC1, dC2, iC0, iC1, iC2);
    ins3b(d11, s1, dD0, dD1, dD2, iD0, iD1, iD2);
  }
  // merge stream-1 into stream-0 per point: all s1 indices > all s0 indices
  ins3(dB0, iB0, dA0, dA1, dA2, iA0, iA1, iA2);
  ins3(dB1, iB1, dA0, dA1, dA2, iA0, iA1, iA2);
  ins3(dB2, iB2, dA0, dA1, dA2, iA0, iA1, iA2);
  ins3(dD0, iD0, dC0, dC1, dC2, iC0, iC1, iC2);
  ins3(dD1, iD1, dC0, dC1, dC2, iC0, iC1, iC2);
  ins3(dD2, iD2, dC0, dC1, dC2, iC0, iC1, iC2);

  {
    const int ra = (pp * 2) * 24 + sub * 3;
    const int rc = ra + 24;
    md[ra + 0] = dA0; md[ra + 1] = dA1; md[ra + 2] = dA2;
    mi[ra + 0] = iA0; mi[ra + 1] = iA1; mi[ra + 2] = iA2;
    md[rc + 0] = dC0; md[rc + 1] = dC1; md[rc + 2] = dC2;
    mi[rc + 0] = iC0; mi[rc + 1] = iC1; mi[rc + 2] = iC2;
  }
  __syncthreads();

  if (sub < 2) {
    const int p = pp * 2 + sub;
    const float tx = sub ? b0 : a0;
    const float ty = sub ? b1 : a1;
    const float tz = sub ? b2 : a2;
    float D0 = 1e30f, D1 = 1e30f, D2 = 1e30f;
    int I0 = 0, I1 = 0, I2 = 0;
    for (int ss = 0; ss < 8; ++ss)          // ascending chunk => earliest index wins ties
      for (int k = 0; k < 3; ++k)
        ins3(md[p * 24 + ss * 3 + k], mi[p * 24 + ss * 3 + k], D0, D1, D2, I0, I1, I2);
    int idxs[3] = {I0, I1, I2};
    float w[3], wsum = 0.f;
    for (int k = 0; k < 3; ++k) {
      float4 sp = sP[idxs[k] + (idxs[k] >> 7)];
      float dx = tx - sp.x, dy = ty - sp.y, dz = tz - sp.z;
      float dd = __fadd_rn(__fadd_rn(__fmul_rn(dx, dx), __fmul_rn(dy, dy)), __fmul_rn(dz, dz));
      w[k] = 1.0f / (dd + 1e-8f);
      wsum += w[k];
    }
    float inv = 1.0f / wsum;
    size_t pt = (size_t)b * 4096 + n0 + p;
    nn[pt * 2 + 0] = make_float4(__int_as_float(I0), __int_as_float(I1), __int_as_float(I2), 0.f);
    nn[pt * 2 + 1] = make_float4(w[0] * inv, w[1] * inv, w[2] * inv, 0.f);
  }
}

// ---------------------------------------------------------------- fused gather+concat+GEMM1
// Block = 64 points x full 256 output cols; 256 threads (4 waves, col-split 1x4).
// LDS ~52KB -> 3 blocks/CU: stage of block k+1 overlaps MFMA of block k.
// Phase 1: build the A tile (64 x 384 bf16) in LDS from L2-resident sfeat
//          gathers + skip. Phase 2: barrier-free K-loop (A from LDS, B frags
//          as coalesced 16B/lane loads from fragment-ordered W1f, L2-hot).
// XCD swizzle: 128 consecutive logical blocks per XCD -> 2 batches (2MB sfeat) per XCD L2.
__global__ __launch_bounds__(256) void gemm1f_kernel(
    const float4* __restrict__ nn, const float* __restrict__ sfeat,
    const float* __restrict__ skip, const u16* __restrict__ W1f,
    u16* __restrict__ Y, float* __restrict__ gs, float* __restrict__ gq) {
  __shared__ u16 As[64 * 392];             // pad 384->392
  __shared__ float csum[256], csq[256];

  const int t = threadIdx.x;
  const int raw = blockIdx.x;
  const int logical = (raw & 7) * 128 + (raw >> 3);   // bijective, 1024 = 8*128
  const int b = logical >> 6;              // batch 0..15
  const int pg = logical & 63;             // point-group of 64
  const size_t n0 = (size_t)b * 4096 + (size_t)pg * 64;

  // ---- phase 1: stage A (4 threads per row; 16B LDS stores)
  {
    const int r = t >> 2, p = t & 3;
    const size_t n = n0 + r;
    float4 nni = nn[n * 2 + 0];
    float4 nnw = nn[n * 2 + 1];
    const int j0 = __float_as_int(nni.x), j1 = __float_as_int(nni.y), j2 = __float_as_int(nni.z);
    const float w0 = nnw.x, w1 = nnw.y, w2 = nnw.z;
    const float4* fb = (const float4*)(sfeat + (size_t)b * 1024 * 256);
    const float4* f0 = fb + (size_t)j0 * 64;
    const float4* f1 = fb + (size_t)j1 * 64;
    const float4* f2 = fb + (size_t)j2 * 64;
    u16* dst = As + r * 392;
#pragma unroll
    for (int v = 0; v < 8; ++v) {
      const int c4 = p * 16 + 2 * v;
      float4 a0 = f0[c4], a1 = f0[c4 + 1];
      float4 b0 = f1[c4], b1 = f1[c4 + 1];
      float4 c0 = f2[c4], c1 = f2[c4 + 1];
      union { uint4 u; u16 s[8]; } o;
      o.s[0] = f2bf(w0 * a0.x + w1 * b0.x + w2 * c0.x);
      o.s[1] = f2bf(w0 * a0.y + w1 * b0.y + w2 * c0.y);
      o.s[2] = f2bf(w0 * a0.z + w1 * b0.z + w2 * c0.z);
      o.s[3] = f2bf(w0 * a0.w + w1 * b0.w + w2 * c0.w);
      o.s[4] = f2bf(w0 * a1.x + w1 * b1.x + w2 * c1.x);
      o.s[5] = f2bf(w0 * a1.y + w1 * b1.y + w2 * c1.y);
      o.s[6] = f2bf(w0 * a1.z + w1 * b1.z + w2 * c1.z);
      o.s[7] = f2bf(w0 * a1.w + w1 * b1.w + w2 * c1.w);
      *(uint4*)(dst + p * 64 + v * 8) = o.u;
    }
    const float4* sk = (const float4*)(skip + n * 128);
#pragma unroll
    for (int v = 0; v < 4; ++v) {
      const int c4 = p * 8 + 2 * v;
      float4 s0 = sk[c4], s1 = sk[c4 + 1];
      union { uint4 u; u16 s[8]; } o;
      o.s[0] = f2bf(s0.x); o.s[1] = f2bf(s0.y); o.s[2] = f2bf(s0.z); o.s[3] = f2bf(s0.w);
      o.s[4] = f2bf(s1.x); o.s[5] = f2bf(s1.y); o.s[6] = f2bf(s1.z); o.s[7] = f2bf(s1.w);
      *(uint4*)(dst + 256 + p * 32 + v * 8) = o.u;
    }
  }
  csum[t] = 0.f; csq[t] = 0.f;
  __syncthreads();

  // ---- phase 2: barrier-free K-loop
  const int w = t >> 6, l = t & 63;
  const int wn = w;                        // col-split: wave w owns cols w*64..w*64+63
  const int lm = l & 15, q = l >> 4;

  f32x4 acc[4][4] = {};
  const u16* Bf = W1f + (wn * 4) * 512 + l * 8;    // (kt*16+g)*512 + l*8

#pragma unroll 4
  for (int kt = 0; kt < 12; ++kt) {
    bf16x8 af[4], bfv[4];
#pragma unroll
    for (int j = 0; j < 4; ++j)
      bfv[j] = *(const bf16x8*)(Bf + kt * 8192 + j * 512);
#pragma unroll
    for (int i = 0; i < 4; ++i)
      af[i] = *(const bf16x8*)&As[(i * 16 + lm) * 392 + kt * 32 + q * 8];
#pragma unroll
    for (int i = 0; i < 4; ++i)
#pragma unroll
      for (int j = 0; j < 4; ++j)
        acc[i][j] = __builtin_amdgcn_mfma_f32_16x16x32_bf16(af[i], bfv[j], acc[i][j], 0, 0, 0);
  }

  // ---- epilogue: bf16 Y1 + column stats
  float lsum[4] = {0, 0, 0, 0}, lsq[4] = {0, 0, 0, 0};
  const int colb = wn * 64;
#pragma unroll
  for (int i = 0; i < 4; ++i) {
    const size_t mg = n0 + i * 16 + q * 4;
#pragma unroll
    for (int r = 0; r < 4; ++r) {
      const size_t ro = (mg + r) * 256;
#pragma unroll
      for (int j = 0; j < 4; ++j) {
        float v = acc[i][j][r];
        Y[ro + colb + j * 16 + lm] = f2bf(v);
        lsum[j] += v; lsq[j] += v * v;
      }
    }
  }
#pragma unroll
  for (int j = 0; j < 4; ++j) {
    atomicAdd(&csum[colb + j * 16 + lm], lsum[j]);
    atomicAdd(&csq[colb + j * 16 + lm], lsq[j]);
  }
  __syncthreads();
  atomicAdd(&gs[t], csum[t]);
  atomicAdd(&gq[t], csq[t]);
}

// ---------------------------------------------------------------- BN finalize (trivial): a=gamma*rsqrt(var+eps), b=beta-mean*a
__global__ void bn_finalize_kernel(const float* __restrict__ stats,
                                   const float* __restrict__ gamma, const float* __restrict__ beta,
                                   float* __restrict__ ab, int C, float invN) {
  int c = threadIdx.x;
  if (c >= C) return;
  float mean = stats[c] * invN;
  float var = stats[C + c] * invN - mean * mean;
  float a = gamma[c] * rsqrtf(var + 1e-5f);
  ab[c] = a;
  ab[C + c] = beta[c] - mean * a;
}

__device__ __forceinline__ uint4 bnrelu_pack(uint4 raw, const float* a1s, const float* b1s, int kb) {
  union { uint4 v; u16 s[8]; } u;
  u.v = raw;
#pragma unroll
  for (int e = 0; e < 8; ++e) {
    float f = fmaxf(bf2f(u.s[e]) * a1s[kb + e] + b1s[kb + e], 0.f);
    u.s[e] = f2bf(f);
  }
  return u.v;
}

// ---------------------------------------------------------------- GEMM2: out = relu(bn1(Y1)) * W2^T
// 64-row tiles, 256 threads (wave grid 2x2), LDS ~37KB -> 4 blocks/CU.
// One-shot A staging with fused bn1+relu, then barrier-free K-loop with
// fragment-ordered W2f from L2.
__global__ __launch_bounds__(256) void gemm2f_kernel(
    const u16* __restrict__ Yin, const u16* __restrict__ W2f,
    const float* __restrict__ ab1, float* __restrict__ out,
    float* __restrict__ gs, float* __restrict__ gq) {
  __shared__ u16 As[64 * 264];             // pad 256->264
  __shared__ float a1s[256], b1s[256];
  __shared__ float csum[128], csq[128];

  const int t = threadIdx.x;
  const int bm = blockIdx.x;               // 1024 blocks, 64 rows each
  a1s[t] = ab1[t];
  b1s[t] = ab1[256 + t];
  if (t < 128) { csum[t] = 0.f; csq[t] = 0.f; }
  __syncthreads();

  // ---- stage A with fused bn1+relu (4 threads per row, 16B stores)
  {
    const int r = t >> 2, x = t & 3;
    const u16* Ag = Yin + (size_t)(bm * 64 + r) * 256 + x * 64;
    u16* dst = As + r * 264 + x * 64;
#pragma unroll
    for (int v = 0; v < 8; ++v) {
      uint4 rawv = *(const uint4*)(Ag + v * 8);
      rawv = bnrelu_pack(rawv, a1s, b1s, x * 64 + v * 8);
      *(uint4*)(dst + v * 8) = rawv;
    }
  }
  __syncthreads();

  const int w = t >> 6, l = t & 63;
  const int wm = w >> 1, wn = w & 1;       // wave grid 2x2: 32 rows x 64 cols each
  const int lm = l & 15, q = l >> 4;

  f32x4 acc[2][4] = {};
  const u16* Bf = W2f + (wn * 4) * 512 + l * 8;    // (kt*8+g)*512 + l*8

#pragma unroll 4
  for (int kt = 0; kt < 8; ++kt) {
    bf16x8 af[2], bfv[4];
#pragma unroll
    for (int j = 0; j < 4; ++j)
      bfv[j] = *(const bf16x8*)(Bf + kt * 4096 + j * 512);
#pragma unroll
    for (int i = 0; i < 2; ++i)
      af[i] = *(const bf16x8*)&As[(wm * 32 + i * 16 + lm) * 264 + kt * 32 + q * 8];
#pragma unroll
    for (int i = 0; i < 2; ++i)
#pragma unroll
      for (int j = 0; j < 4; ++j)
        acc[i][j] = __builtin_amdgcn_mfma_f32_16x16x32_bf16(af[i], bfv[j], acc[i][j], 0, 0, 0);
  }

  float lsum[4] = {0, 0, 0, 0}, lsq[4] = {0, 0, 0, 0};
  const int colb = wn * 64;
#pragma unroll
  for (int i = 0; i < 2; ++i) {
    const int mg = bm * 64 + wm * 32 + i * 16 + q * 4;
#pragma unroll
    for (int r = 0; r < 4; ++r) {
      const size_t ro = (size_t)(mg + r) * 128;
#pragma unroll
      for (int j = 0; j < 4; ++j) {
        float v = acc[i][j][r];
        out[ro + colb + j * 16 + lm] = v;
        lsum[j] += v; lsq[j] += v * v;
      }
    }
  }
#pragma unroll
  for (int j = 0; j < 4; ++j) {
    atomicAdd(&csum[colb + j * 16 + lm], lsum[j]);
    atomicAdd(&csq[colb + j * 16 + lm], lsq[j]);
  }
  __syncthreads();
  if (t < 128) {
    atomicAdd(&gs[t], csum[t]);
    atomicAdd(&gq[t], csq[t]);
  }
}

// ---------------------------------------------------------------- final BN2+ReLU in place on d_out
__global__ __launch_bounds__(256) void bn_relu_out_kernel(float* __restrict__ out,
                                                          const float* __restrict__ ab2) {
  int idx = blockIdx.x * 256 + threadIdx.x;   // 8192*256 = 2097152 = exactly out_size/4
  float4* o4 = (float4*)out;
  float4 v = o4[idx];
  int c = (idx * 4) & 127;
  v.x = fmaxf(v.x * ab2[c + 0] + ab2[128 + c + 0], 0.f);
  v.y = fmaxf(v.y * ab2[c + 1] + ab2[128 + c + 1], 0.f);
  v.z = fmaxf(v.z * ab2[c + 2] + ab2[128 + c + 2], 0.f);
  v.w = fmaxf(v.w * ab2[c + 3] + ab2[128 + c + 3], 0.f);
  o4[idx] = v;
}

extern "C" void kernel_launch(void* const* d_in, const int* in_sizes, int n_in,
                              void* d_out, int out_size, void* d_ws, size_t ws_size,
                              hipStream_t stream) {
  const float* txyz  = (const float*)d_in[0];
  const float* sxyz  = (const float*)d_in[1];
  const float* sfeat = (const float*)d_in[2];
  const float* skip  = (const float*)d_in[3];
  const float* W1    = (const float*)d_in[4];
  const float* g1    = (const float*)d_in[5];
  const float* be1   = (const float*)d_in[6];
  const float* W2    = (const float*)d_in[7];
  const float* g2    = (const float*)d_in[8];
  const float* be2   = (const float*)d_in[9];
  float* out = (float*)d_out;

  char* ws = (char*)d_ws;
  u16*    Y1  = (u16*)(ws + 0ull);                // 65536*256*2 = 33554432
  float4* nnd = (float4*)(ws + 33554432ull);      // 65536*32   =  2097152
  u16*    W1f = (u16*)(ws + 35651584ull);         // 196608
  u16*    W2f = (u16*)(ws + 35848192ull);         // 65536
  float*  stats = (float*)(ws + 35913728ull);     // 768*4: gs1[256] gq1[256] gs2[128] gq2[128]
  float*  ab1 = (float*)(ws + 35916800ull);       // 512*4
  float*  ab2 = (float*)(ws + 35918848ull);       // 256*4

  conv_w_kernel<<<512, 256, 0, stream>>>(W1, W2, W1f, W2f, stats);
  knn_kernel<<<1024, 256, 0, stream>>>(txyz, sxyz, nnd);
  gemm1f_kernel<<<1024, 256, 0, stream>>>(nnd, sfeat, skip, W1f, Y1, stats, stats + 256);
  bn_finalize_kernel<<<1, 256, 0, stream>>>(stats, g1, be1, ab1, 256, 1.0f / 65536.0f);
  gemm2f_kernel<<<1024, 256, 0, stream>>>(Y1, W2f, ab1, out, stats + 512, stats + 640);
  bn_finalize_kernel<<<1, 128, 0, stream>>>(stats + 512, g2, be2, ab2, 128, 1.0f / 65536.0f);
  bn_relu_out_kernel<<<8192, 256, 0, stream>>>(out, ab2);
}

// Round 3
// 266.249 us; speedup vs baseline: 1.0398x; 1.0398x over previous
//
#include <hip/hip_runtime.h>

typedef unsigned short u16;
typedef unsigned int u32;

typedef __bf16 bf16x8 __attribute__((ext_vector_type(8)));
typedef float f32x4 __attribute__((ext_vector_type(4)));

__device__ __forceinline__ u16 f2bf(float f) {
  u32 u = __float_as_uint(f);
  u = u + 0x7fffu + ((u >> 16) & 1u);
  return (u16)(u >> 16);
}
__device__ __forceinline__ float bf2f(u16 u) {
  return __uint_as_float(((u32)u) << 16);
}

// strict-< insertion keeps earliest index on ties (matches jax.lax.top_k)
__device__ __forceinline__ void ins3(float d, int s,
                                     float& d0, float& d1, float& d2,
                                     int& i0, int& i1, int& i2) {
  if (d < d2) {
    if (d < d1) {
      d2 = d1; i2 = i1;
      if (d < d0) { d1 = d0; i1 = i0; d0 = d; i0 = s; }
      else        { d1 = d; i1 = s; }
    } else { d2 = d; i2 = s; }
  }
}

// branchless strict-< top-3 insert: 3 cmp + 10 cndmask
__device__ __forceinline__ void ins3b(float d, int s,
                                      float& d0, float& d1, float& d2,
                                      int& i0, int& i1, int& i2) {
  bool c2 = d < d2, c1 = d < d1, c0 = d < d0;
  d2 = c1 ? d1 : (c2 ? d : d2);
  i2 = c1 ? i1 : (c2 ? s : i2);
  d1 = c0 ? d0 : (c1 ? d : d1);
  i1 = c0 ? i0 : (c1 ? s : i1);
  d0 = c0 ? d : d0;
  i0 = c0 ? s : i0;
}

// ---------------------------------------------------------------- weights -> bf16 in MFMA-fragment order + zero BN stat accumulators
// W1f layout: [kt=12][g=16][lane=64][e=8] : element = W1[g*16 + (l&15)][kt*32 + (l>>4)*8 + e]
// W2f layout: [kt= 8][g= 8][lane=64][e=8] : element = W2[g*16 + (l&15)][kt*32 + (l>>4)*8 + e]
__global__ __launch_bounds__(256) void conv_w_kernel(
    const float* __restrict__ W1, const float* __restrict__ W2,
    u16* __restrict__ W1f, u16* __restrict__ W2f, float* __restrict__ stats) {
  int i = blockIdx.x * 256 + threadIdx.x;      // 512 blocks * 256 = 131072 exactly
  if (i < 98304) {
    int e = i & 7, l = (i >> 3) & 63, g = (i >> 9) & 15, kt = i >> 13;
    int col = g * 16 + (l & 15);
    int k = kt * 32 + (l >> 4) * 8 + e;
    W1f[i] = f2bf(W1[col * 384 + k]);
  } else {
    int j = i - 98304;                         // 0..32767
    int e = j & 7, l = (j >> 3) & 63, g = (j >> 9) & 7, kt = j >> 12;
    int col = g * 16 + (l & 15);
    int k = kt * 32 + (l >> 4) * 8 + e;
    W2f[j] = f2bf(W2[col * 256 + k]);
  }
  if (i < 768) stats[i] = 0.f;                 // gs1[256] gq1[256] gs2[128] gq2[128]
}

// ---------------------------------------------------------------- 3NN: indices + weights per point
// 256 threads = 64 target points, 2 points per thread x 8 sub-scans of 128
// sources; one ds_read_b128 serves two point-distance computations and each
// thread runs 4 independent cmp->cndmask chains (ILP). Ascending chunk split
// keeps tie-break exact. LDS ~28.8KB -> 5 blocks/CU (grid 1024 = 4/CU, no tail).
__global__ __launch_bounds__(256) void knn_kernel(
    const float* __restrict__ txyz, const float* __restrict__ sxyz,
    float4* __restrict__ nn) {
  __shared__ float4 sP[1032];      // padded: index s + (s>>7)
  __shared__ float  md[64 * 24];
  __shared__ int    mi[64 * 24];

  const int t = threadIdx.x;
  const int b = blockIdx.x >> 6;              // grid 1024 = 16 batches * 64 groups
  const int n0 = (blockIdx.x & 63) << 6;      // 64 points per block

  const float* sb = sxyz + (size_t)b * 1024 * 3;
  for (int i = t; i < 1024; i += 256) {
    float x = sb[i * 3 + 0], y = sb[i * 3 + 1], z = sb[i * 3 + 2];
    float r2 = __fadd_rn(__fadd_rn(__fmul_rn(x, x), __fmul_rn(y, y)), __fmul_rn(z, z));
    sP[i + (i >> 7)] = make_float4(x, y, z, r2);
  }
  __syncthreads();

  const int pp = t >> 3, sub = t & 7;
  const int nA = n0 + pp * 2;
  const float* ta = txyz + ((size_t)b * 4096 + nA) * 3;
  const float a0 = ta[0], a1 = ta[1], a2 = ta[2];
  const float b0 = ta[3], b1 = ta[4], b2 = ta[5];
  const float q2a = __fadd_rn(__fadd_rn(__fmul_rn(a0, a0), __fmul_rn(a1, a1)), __fmul_rn(a2, a2));
  const float q2b = __fadd_rn(__fadd_rn(__fmul_rn(b0, b0), __fmul_rn(b1, b1)), __fmul_rn(b2, b2));

  float dA0 = 1e30f, dA1 = 1e30f, dA2 = 1e30f; int iA0 = 0, iA1 = 0, iA2 = 0;
  float dB0 = 1e30f, dB1 = 1e30f, dB2 = 1e30f; int iB0 = 0, iB1 = 0, iB2 = 0;
  float dC0 = 1e30f, dC1 = 1e30f, dC2 = 1e30f; int iC0 = 0, iC1 = 0, iC2 = 0;
  float dD0 = 1e30f, dD1 = 1e30f, dD2 = 1e30f; int iD0 = 0, iD1 = 0, iD2 = 0;
  const int sbeg = sub * 128;

#pragma unroll 4
  for (int off = 0; off < 64; ++off) {
    const int s0 = sbeg + off;
    const int s1 = sbeg + 64 + off;
    float4 p0 = sP[s0 + (s0 >> 7)];
    float4 p1 = sP[s1 + (s1 >> 7)];

    float c00 = __fmul_rn(a0, p0.x);
    c00 = __fadd_rn(c00, __fmul_rn(a1, p0.y));
    c00 = __fadd_rn(c00, __fmul_rn(a2, p0.z));
    float d00 = fmaxf(__fadd_rn(__fadd_rn(q2a, p0.w), __fmul_rn(-2.0f, c00)), 0.0f);

    float c01 = __fmul_rn(a0, p1.x);
    c01 = __fadd_rn(c01, __fmul_rn(a1, p1.y));
    c01 = __fadd_rn(c01, __fmul_rn(a2, p1.z));
    float d01 = fmaxf(__fadd_rn(__fadd_rn(q2a, p1.w), __fmul_rn(-2.0f, c01)), 0.0f);

    float c10 = __fmul_rn(b0, p0.x);
    c10 = __fadd_rn(c10, __fmul_rn(b1, p0.y));
    c10 = __fadd_rn(c10, __fmul_rn(b2, p0.z));
    float d10 = fmaxf(__fadd_rn(__fadd_rn(q2b, p0.w), __fmul_rn(-2.0f, c10)), 0.0f);

    float c11 = __fmul_rn(b0, p1.x);
    c11 = __fadd_rn(c11, __fmul_rn(b1, p1.y));
    c11 = __fadd_rn(c11, __fmul_rn(b2, p1.z));
    float d11 = fmaxf(__fadd_rn(__fadd_rn(q2b, p1.w), __fmul_rn(-2.0f, c11)), 0.0f);

    ins3b(d00, s0, dA0, dA1, dA2, iA0, iA1, iA2);
    ins3b(d01, s1, dB0, dB1, dB2, iB0, iB1, iB2);
    ins3b(d10, s0, dC0, dC1, dC2, iC0, iC1, iC2);
    ins3b(d11, s1, dD0, dD1, dD2, iD0, iD1, iD2);
  }
  ins3(dB0, iB0, dA0, dA1, dA2, iA0, iA1, iA2);
  ins3(dB1, iB1, dA0, dA1, dA2, iA0, iA1, iA2);
  ins3(dB2, iB2, dA0, dA1, dA2, iA0, iA1, iA2);
  ins3(dD0, iD0, dC0, dC1, dC2, iC0, iC1, iC2);
  ins3(dD1, iD1, dC0, dC1, dC2, iC0, iC1, iC2);
  ins3(dD2, iD2, dC0, dC1, dC2, iC0, iC1, iC2);

  {
    const int ra = (pp * 2) * 24 + sub * 3;
    const int rc = ra + 24;
    md[ra + 0] = dA0; md[ra + 1] = dA1; md[ra + 2] = dA2;
    mi[ra + 0] = iA0; mi[ra + 1] = iA1; mi[ra + 2] = iA2;
    md[rc + 0] = dC0; md[rc + 1] = dC1; md[rc + 2] = dC2;
    mi[rc + 0] = iC0; mi[rc + 1] = iC1; mi[rc + 2] = iC2;
  }
  __syncthreads();

  if (sub < 2) {
    const int p = pp * 2 + sub;
    const float tx = sub ? b0 : a0;
    const float ty = sub ? b1 : a1;
    const float tz = sub ? b2 : a2;
    float D0 = 1e30f, D1 = 1e30f, D2 = 1e30f;
    int I0 = 0, I1 = 0, I2 = 0;
    for (int ss = 0; ss < 8; ++ss)          // ascending chunk => earliest index wins ties
      for (int k = 0; k < 3; ++k)
        ins3(md[p * 24 + ss * 3 + k], mi[p * 24 + ss * 3 + k], D0, D1, D2, I0, I1, I2);
    int idxs[3] = {I0, I1, I2};
    float w[3], wsum = 0.f;
    for (int k = 0; k < 3; ++k) {
      float4 sp = sP[idxs[k] + (idxs[k] >> 7)];
      float dx = tx - sp.x, dy = ty - sp.y, dz = tz - sp.z;
      float dd = __fadd_rn(__fadd_rn(__fmul_rn(dx, dx), __fmul_rn(dy, dy)), __fmul_rn(dz, dz));
      w[k] = 1.0f / (dd + 1e-8f);
      wsum += w[k];
    }
    float inv = 1.0f / wsum;
    size_t pt = (size_t)b * 4096 + n0 + p;
    nn[pt * 2 + 0] = make_float4(__int_as_float(I0), __int_as_float(I1), __int_as_float(I2), 0.f);
    nn[pt * 2 + 1] = make_float4(w[0] * inv, w[1] * inv, w[2] * inv, 0.f);
  }
}

// ---------------------------------------------------------------- fused gather+concat+GEMM1
// 64-row tile, 256 threads, LDS 52224B -> 3 blocks/CU.
// Phase 1 (wave-coalesced): wave w stages rows 16w..16w+15. Per row, lane l
// reads fb4[j*64+l] -> each load instr is one contiguous 1KB row (full lines,
// 4x fewer L1/L2 transactions than per-thread chunking). NN idx/weights are
// loaded once per wave (coalesced) and broadcast per row via __shfl.
// Phase 2: barrier-free K-loop (A frags from LDS, B frags 16B/lane coalesced
// from fragment-ordered W1f, L2-hot).
__global__ __launch_bounds__(256) void gemm1f_kernel(
    const float4* __restrict__ nn, const float* __restrict__ sfeat,
    const float* __restrict__ skip, const u16* __restrict__ W1f,
    u16* __restrict__ Y, float* __restrict__ gs, float* __restrict__ gq) {
  __shared__ u16 As[64 * 392];             // pad 384->392
  __shared__ float csum[256], csq[256];

  const int t = threadIdx.x;
  const int raw = blockIdx.x;
  const int logical = (raw & 7) * 128 + (raw >> 3);   // bijective, 1024 = 8*128
  const int b = logical >> 6;              // batch 0..15
  const int pg = logical & 63;             // point-group of 64
  const size_t n0 = (size_t)b * 4096 + (size_t)pg * 64;

  const int w = t >> 6, l = t & 63;

  // ---- phase 1: wave-coalesced staging; wave w stages rows 16w..16w+15
  {
    const int r0 = w * 16;
    // nn for this wave's 16 rows: 32 float4s -> lanes (lanes>=32 duplicate)
    float4 my = nn[(n0 + r0) * 2 + (l & 31)];
    const float4* fb4 = (const float4*)(sfeat + (size_t)b * 1024 * 256);
#pragma unroll 4
    for (int r = 0; r < 16; ++r) {
      int j0 = __float_as_int(__shfl(my.x, 2 * r));
      int j1 = __float_as_int(__shfl(my.y, 2 * r));
      int j2 = __float_as_int(__shfl(my.z, 2 * r));
      float w0 = __shfl(my.x, 2 * r + 1);
      float w1 = __shfl(my.y, 2 * r + 1);
      float w2 = __shfl(my.z, 2 * r + 1);
      float4 A  = fb4[(size_t)j0 * 64 + l];
      float4 Bv = fb4[(size_t)j1 * 64 + l];
      float4 Cv = fb4[(size_t)j2 * 64 + l];
      ushort4 o;
      o.x = f2bf(w0 * A.x + w1 * Bv.x + w2 * Cv.x);
      o.y = f2bf(w0 * A.y + w1 * Bv.y + w2 * Cv.y);
      o.z = f2bf(w0 * A.z + w1 * Bv.z + w2 * Cv.z);
      o.w = f2bf(w0 * A.w + w1 * Bv.w + w2 * Cv.w);
      *(ushort4*)&As[(r0 + r) * 392 + 4 * l] = o;
    }
    // skip: 16 rows x 128 floats = 8 iters x (64 lanes x float4, 1KB contiguous)
    const float4* sk4 = (const float4*)(skip + (n0 + r0) * 128);
#pragma unroll 4
    for (int it = 0; it < 8; ++it) {
      int rr = 2 * it + (l >> 5);
      int cc = l & 31;
      float4 s = sk4[it * 64 + l];
      ushort4 o;
      o.x = f2bf(s.x); o.y = f2bf(s.y); o.z = f2bf(s.z); o.w = f2bf(s.w);
      *(ushort4*)&As[(r0 + rr) * 392 + 256 + 4 * cc] = o;
    }
  }
  csum[t] = 0.f; csq[t] = 0.f;
  __syncthreads();

  // ---- phase 2: barrier-free K-loop
  const int wn = w;                        // col-split: wave w owns cols w*64..w*64+63
  const int lm = l & 15, q = l >> 4;

  f32x4 acc[4][4] = {};
  const u16* Bf = W1f + (wn * 4) * 512 + l * 8;    // (kt*16+g)*512 + l*8

#pragma unroll 4
  for (int kt = 0; kt < 12; ++kt) {
    bf16x8 af[4], bfv[4];
#pragma unroll
    for (int j = 0; j < 4; ++j)
      bfv[j] = *(const bf16x8*)(Bf + kt * 8192 + j * 512);
#pragma unroll
    for (int i = 0; i < 4; ++i)
      af[i] = *(const bf16x8*)&As[(i * 16 + lm) * 392 + kt * 32 + q * 8];
#pragma unroll
    for (int i = 0; i < 4; ++i)
#pragma unroll
      for (int j = 0; j < 4; ++j)
        acc[i][j] = __builtin_amdgcn_mfma_f32_16x16x32_bf16(af[i], bfv[j], acc[i][j], 0, 0, 0);
  }

  // ---- epilogue: bf16 Y1 + column stats
  float lsum[4] = {0, 0, 0, 0}, lsq[4] = {0, 0, 0, 0};
  const int colb = wn * 64;
#pragma unroll
  for (int i = 0; i < 4; ++i) {
    const size_t mg = n0 + i * 16 + q * 4;
#pragma unroll
    for (int r = 0; r < 4; ++r) {
      const size_t ro = (mg + r) * 256;
#pragma unroll
      for (int j = 0; j < 4; ++j) {
        float v = acc[i][j][r];
        Y[ro + colb + j * 16 + lm] = f2bf(v);
        lsum[j] += v; lsq[j] += v * v;
      }
    }
  }
#pragma unroll
  for (int j = 0; j < 4; ++j) {
    atomicAdd(&csum[colb + j * 16 + lm], lsum[j]);
    atomicAdd(&csq[colb + j * 16 + lm], lsq[j]);
  }
  __syncthreads();
  atomicAdd(&gs[t], csum[t]);
  atomicAdd(&gq[t], csq[t]);
}

__device__ __forceinline__ uint4 bnrelu_pack(uint4 raw, const float* a1s, const float* b1s, int kb) {
  union { uint4 v; u16 s[8]; } u;
  u.v = raw;
#pragma unroll
  for (int e = 0; e < 8; ++e) {
    float f = fmaxf(bf2f(u.s[e]) * a1s[kb + e] + b1s[kb + e], 0.f);
    u.s[e] = f2bf(f);
  }
  return u.v;
}

// ---------------------------------------------------------------- GEMM2: out = relu(bn1(Y1)) * W2^T
// 64-row tiles, 256 threads (wave grid 2x2), LDS ~36.9KB -> 4 blocks/CU (grid
// 1024 = exact fit, no tail). BN1 finalize is computed in-block from the raw
// stats (removes a 1-block kernel launch + its bubble). A-stage is
// wave-coalesced: 1KB contiguous per load instruction.
__global__ __launch_bounds__(256) void gemm2f_kernel(
    const u16* __restrict__ Yin, const u16* __restrict__ W2f,
    const float* __restrict__ stats, const float* __restrict__ g1,
    const float* __restrict__ be1, float* __restrict__ out,
    float* __restrict__ gs, float* __restrict__ gq) {
  __shared__ u16 As[64 * 264];             // pad 256->264
  __shared__ float a1s[256], b1s[256];
  __shared__ float csum[128], csq[128];

  const int t = threadIdx.x;
  const int bm = blockIdx.x;               // 1024 blocks, 64 rows each

  // BN1 finalize in-block (same arithmetic as the old bn_finalize kernel)
  {
    const float invN = 1.0f / 65536.0f;
    float mean = stats[t] * invN;
    float var = stats[256 + t] * invN - mean * mean;
    float a = g1[t] * rsqrtf(var + 1e-5f);
    a1s[t] = a;
    b1s[t] = be1[t] - mean * a;
  }
  if (t < 128) { csum[t] = 0.f; csq[t] = 0.f; }
  __syncthreads();

  // ---- stage A with fused bn1+relu; wave w stages rows 16w..16w+15
  const int w = t >> 6, l = t & 63;
  {
    const int r0 = w * 16;
#pragma unroll 4
    for (int it = 0; it < 8; ++it) {
      const int rr = r0 + 2 * it + (l >> 5);
      const int kb = (l & 31) * 8;
      uint4 rawv = *(const uint4*)(Yin + (size_t)(bm * 64 + rr) * 256 + kb);
      rawv = bnrelu_pack(rawv, a1s, b1s, kb);
      *(uint4*)&As[rr * 264 + kb] = rawv;
    }
  }
  __syncthreads();

  const int wm = w >> 1, wn = w & 1;       // wave grid 2x2: 32 rows x 64 cols each
  const int lm = l & 15, q = l >> 4;

  f32x4 acc[2][4] = {};
  const u16* Bf = W2f + (wn * 4) * 512 + l * 8;    // (kt*8+g)*512 + l*8

#pragma unroll 4
  for (int kt = 0; kt < 8; ++kt) {
    bf16x8 af[2], bfv[4];
#pragma unroll
    for (int j = 0; j < 4; ++j)
      bfv[j] = *(const bf16x8*)(Bf + kt * 4096 + j * 512);
#pragma unroll
    for (int i = 0; i < 2; ++i)
      af[i] = *(const bf16x8*)&As[(wm * 32 + i * 16 + lm) * 264 + kt * 32 + q * 8];
#pragma unroll
    for (int i = 0; i < 2; ++i)
#pragma unroll
      for (int j = 0; j < 4; ++j)
        acc[i][j] = __builtin_amdgcn_mfma_f32_16x16x32_bf16(af[i], bfv[j], acc[i][j], 0, 0, 0);
  }

  float lsum[4] = {0, 0, 0, 0}, lsq[4] = {0, 0, 0, 0};
  const int colb = wn * 64;
#pragma unroll
  for (int i = 0; i < 2; ++i) {
    const int mg = bm * 64 + wm * 32 + i * 16 + q * 4;
#pragma unroll
    for (int r = 0; r < 4; ++r) {
      const size_t ro = (size_t)(mg + r) * 128;
#pragma unroll
      for (int j = 0; j < 4; ++j) {
        float v = acc[i][j][r];
        out[ro + colb + j * 16 + lm] = v;
        lsum[j] += v; lsq[j] += v * v;
      }
    }
  }
#pragma unroll
  for (int j = 0; j < 4; ++j) {
    atomicAdd(&csum[colb + j * 16 + lm], lsum[j]);
    atomicAdd(&csq[colb + j * 16 + lm], lsq[j]);
  }
  __syncthreads();
  if (t < 128) {
    atomicAdd(&gs[t], csum[t]);
    atomicAdd(&gq[t], csq[t]);
  }
}

// ---------------------------------------------------------------- final BN2+ReLU in place on d_out (BN2 finalize computed in-block)
__global__ __launch_bounds__(256) void bn_relu_out_kernel(
    float* __restrict__ out, const float* __restrict__ stats2,
    const float* __restrict__ g2, const float* __restrict__ be2) {
  __shared__ float a2[128], b2[128];
  int t = threadIdx.x;
  if (t < 128) {
    const float invN = 1.0f / 65536.0f;
    float mean = stats2[t] * invN;
    float var = stats2[128 + t] * invN - mean * mean;
    float a = g2[t] * rsqrtf(var + 1e-5f);
    a2[t] = a;
    b2[t] = be2[t] - mean * a;
  }
  __syncthreads();
  int idx = blockIdx.x * 256 + t;             // 8192*256 = 2097152 = exactly out_size/4
  float4* o4 = (float4*)out;
  float4 v = o4[idx];
  int c = (idx * 4) & 127;
  v.x = fmaxf(v.x * a2[c + 0] + b2[c + 0], 0.f);
  v.y = fmaxf(v.y * a2[c + 1] + b2[c + 1], 0.f);
  v.z = fmaxf(v.z * a2[c + 2] + b2[c + 2], 0.f);
  v.w = fmaxf(v.w * a2[c + 3] + b2[c + 3], 0.f);
  o4[idx] = v;
}

extern "C" void kernel_launch(void* const* d_in, const int* in_sizes, int n_in,
                              void* d_out, int out_size, void* d_ws, size_t ws_size,
                              hipStream_t stream) {
  const float* txyz  = (const float*)d_in[0];
  const float* sxyz  = (const float*)d_in[1];
  const float* sfeat = (const float*)d_in[2];
  const float* skip  = (const float*)d_in[3];
  const float* W1    = (const float*)d_in[4];
  const float* g1    = (const float*)d_in[5];
  const float* be1   = (const float*)d_in[6];
  const float* W2    = (const float*)d_in[7];
  const float* g2    = (const float*)d_in[8];
  const float* be2   = (const float*)d_in[9];
  float* out = (float*)d_out;

  char* ws = (char*)d_ws;
  u16*    Y1  = (u16*)(ws + 0ull);                // 65536*256*2 = 33554432
  float4* nnd = (float4*)(ws + 33554432ull);      // 65536*32   =  2097152
  u16*    W1f = (u16*)(ws + 35651584ull);         // 196608
  u16*    W2f = (u16*)(ws + 35848192ull);         // 65536
  float*  stats = (float*)(ws + 35913728ull);     // 768*4: gs1[256] gq1[256] gs2[128] gq2[128]

  conv_w_kernel<<<512, 256, 0, stream>>>(W1, W2, W1f, W2f, stats);
  knn_kernel<<<1024, 256, 0, stream>>>(txyz, sxyz, nnd);
  gemm1f_kernel<<<1024, 256, 0, stream>>>(nnd, sfeat, skip, W1f, Y1, stats, stats + 256);
  gemm2f_kernel<<<1024, 256, 0, stream>>>(Y1, W2f, stats, g1, be1, out, stats + 512, stats + 640);
  bn_relu_out_kernel<<<8192, 256, 0, stream>>>(out, stats + 512, g2, be2);
}